// Round 2
// baseline (1803.557 us; speedup 1.0000x reference)
//
#include <hip/hip_runtime.h>

// RSNEncoder: 8-step GRU (B=32768, D=512) + odd-step linear mix.
// R2: 256x256-tile 8-wave GEMM, counted-vmcnt double-buffer (T3/T4), T2 LDS
// XOR-swizzle, T5 setprio, T1 XCD swizzle. Gates GEMM padded to N=2048 with
// column "kinds" {r, z, i_n(K<512), h_n(K>=512)}; gate math in LDS-combine
// epilogue. h state is bf16-only.

#define BDIM 32768
#define DDIM 512
#define BD (BDIM * DDIM)

typedef short bf16x8 __attribute__((ext_vector_type(8)));
typedef float f32x4 __attribute__((ext_vector_type(4)));
typedef unsigned short u16x8 __attribute__((ext_vector_type(8)));

__device__ __forceinline__ unsigned short f2bf(float f) {
  union { float f; unsigned u; } v; v.f = f;
  return (unsigned short)((v.u + 0x7fffu + ((v.u >> 16) & 1u)) >> 16);  // RNE
}
__device__ __forceinline__ float bf2f(unsigned short b) {
  union { unsigned u; float f; } v; v.u = (unsigned)b << 16; return v.f;
}
__device__ __forceinline__ float sigmf(float x) { return 1.0f / (1.0f + __expf(-x)); }
__device__ __forceinline__ float tanhf_(float x) { return 1.0f - 2.0f / (__expf(2.0f * x) + 1.0f); }
__device__ __forceinline__ void bar() { asm volatile("s_barrier" ::: "memory"); }

// ---- fp32 -> bf16, all 8 steps of x in one launch ----
__global__ void cvt_bf16_all(const float* __restrict__ in, unsigned short* __restrict__ out) {
  const size_t i = ((size_t)blockIdx.x * 256 + threadIdx.x) * 8;
  const float4 a = *(const float4*)(in + i);
  const float4 b = *(const float4*)(in + i + 4);
  u16x8 o;
  o[0] = f2bf(a.x); o[1] = f2bf(a.y); o[2] = f2bf(a.z); o[3] = f2bf(a.w);
  o[4] = f2bf(b.x); o[5] = f2bf(b.y); o[6] = f2bf(b.z); o[7] = f2bf(b.w);
  *(u16x8*)(out + i) = o;
}

// ---- weight prep ----
// Wg[2048][1024]: row c = dblk*256 + kind*64 + dd (d = dblk*64+dd)
//   kind0 r: [Wih_r | Whh_r]; kind1 z: [Wih_z | Whh_z]
//   kind2 i_n: [Wih_n | 0]  ; kind3 h_n: [0 | Whh_n]
// Wm[512][1024] = [w1 | w2]
__global__ void prep_w(const float* __restrict__ wih, const float* __restrict__ whh,
                       const float* __restrict__ w1, const float* __restrict__ w2,
                       unsigned short* __restrict__ Wg, unsigned short* __restrict__ Wm) {
  int i = blockIdx.x * 256 + threadIdx.x;
  if (i < 2048 * 1024) {
    const int c = i >> 10, k = i & 1023;
    const int dblk = c >> 8, kind = (c >> 6) & 3, dd = c & 63;
    const int d = dblk * 64 + dd;
    float v;
    if (kind == 0)      v = (k < 512) ? wih[d * 512 + k] : whh[d * 512 + (k - 512)];
    else if (kind == 1) v = (k < 512) ? wih[(512 + d) * 512 + k] : whh[(512 + d) * 512 + (k - 512)];
    else if (kind == 2) v = (k < 512) ? wih[(1024 + d) * 512 + k] : 0.0f;
    else                v = (k < 512) ? 0.0f : whh[(1024 + d) * 512 + (k - 512)];
    Wg[i] = f2bf(v);
  } else {
    i -= 2048 * 1024;
    const int j = i >> 10, k = i & 1023;
    Wm[i] = f2bf((k < 512) ? w1[j * 512 + k] : w2[j * 512 + (k - 512)]);
  }
}

// ---- 256x256 8-wave GEMM, counted-vmcnt double buffer ----
// KINDS=4: gates (N=2048, kind-encoded cols, gate-combine epilogue)
// KINDS=1: mixed (N=512, direct epilogue)
// A = [A0 | A1] along K (each [32768][512] bf16). W row stride 2048 B. K=1024.
template <int KINDS, int NB>
__global__ __launch_bounds__(512, 2) void gemm8(
    const unsigned short* __restrict__ A0, const unsigned short* A1,
    const unsigned short* __restrict__ W,
    const float* __restrict__ bih, const float* __restrict__ bhh,
    const unsigned short* hold,             // bf16 h_old (gates only; may alias A1)
    unsigned short* __restrict__ outB, float* __restrict__ outF, int writeF) {
  __shared__ char smem[131072];  // 2 bufs x (A 32K + B 32K)

  const int t = threadIdx.x;
  const int lane = t & 63, wid = t >> 6;
  const int wm = wid >> 2, wn = wid & 3;

  // T1: same-bm blocks (sharing the A panel) land on one XCD
  const int xcd = blockIdx.x & 7;
  const int ixc = blockIdx.x >> 3;
  const int bm = xcd * 16 + ixc / NB;   // NBM = 128
  const int bn = ixc % NB;

  f32x4 acc[8][4];
  const f32x4 z4 = {0.f, 0.f, 0.f, 0.f};
#pragma unroll
  for (int a = 0; a < 8; ++a)
#pragma unroll
    for (int b = 0; b < 4; ++b) acc[a][b] = z4;

  // Stage constants: instance inst covers LDS bytes o = inst*8192 + wid*1024 + lane*16
  // of a 32 KB [256 rows][128 B] tile. Source col-slot pre-swizzled (rule #21).
  int aoff[4], boff[4];
#pragma unroll
  for (int inst = 0; inst < 4; ++inst) {
    const int o = inst * 8192 + wid * 1024 + lane * 16;
    const int r = o >> 7, cb = o & 127;
    const int scb = cb ^ ((r & 7) << 4);
    aoff[inst] = (bm * 256 + r) * 1024 + scb;   // A row stride 1024 B
    boff[inst] = (bn * 256 + r) * 2048 + scb;   // W row stride 2048 B
  }

  auto STAGE = [&](int kt, int buf) {
    const char* Abase = (const char*)(kt < 8 ? A0 : A1) + (kt & 7) * 128;
    const char* Bbase = (const char*)W + kt * 128;
    char* la = smem + buf * 65536 + wid * 1024;
#pragma unroll
    for (int inst = 0; inst < 4; ++inst)
      __builtin_amdgcn_global_load_lds(
          (const __attribute__((address_space(1))) void*)(Abase + aoff[inst]),
          (__attribute__((address_space(3))) void*)(la + inst * 8192), 16, 0, 0);
#pragma unroll
    for (int inst = 0; inst < 4; ++inst)
      __builtin_amdgcn_global_load_lds(
          (const __attribute__((address_space(1))) void*)(Bbase + boff[inst]),
          (__attribute__((address_space(3))) void*)(la + 32768 + inst * 8192), 16, 0, 0);
  };

  STAGE(0, 0);
  STAGE(1, 1);
  asm volatile("s_waitcnt vmcnt(8)" ::: "memory");  // tile0 arrived, tile1 in flight
  bar();

  for (int kt = 0; kt < 16; ++kt) {
    const int cur = kt & 1;
    const char* pa = smem + cur * 65536;
    const char* pb = pa + 32768;
#pragma unroll
    for (int q = 0; q < 4; ++q) {  // C-quadrants: (mh, nh)
      const int mh = q >> 1, nh = q & 1;
      bf16x8 af[4][2], bfr[2][2];
#pragma unroll
      for (int fm = 0; fm < 4; ++fm)
#pragma unroll
        for (int ks = 0; ks < 2; ++ks) {
          const int row = wm * 128 + mh * 64 + fm * 16 + (lane & 15);
          const int c = ks * 64 + (lane >> 4) * 16;
          af[fm][ks] = *(const bf16x8*)(pa + row * 128 + (c ^ ((row & 7) << 4)));
        }
#pragma unroll
      for (int fn = 0; fn < 2; ++fn)
#pragma unroll
        for (int ks = 0; ks < 2; ++ks) {
          const int row = wn * 64 + nh * 32 + fn * 16 + (lane & 15);
          const int c = ks * 64 + (lane >> 4) * 16;
          bfr[fn][ks] = *(const bf16x8*)(pb + row * 128 + (c ^ ((row & 7) << 4)));
        }
      __builtin_amdgcn_s_setprio(1);
#pragma unroll
      for (int fm = 0; fm < 4; ++fm)
#pragma unroll
        for (int fn = 0; fn < 2; ++fn)
#pragma unroll
          for (int ks = 0; ks < 2; ++ks)
            acc[mh * 4 + fm][nh * 2 + fn] = __builtin_amdgcn_mfma_f32_16x16x32_bf16(
                af[fm][ks], bfr[fn][ks], acc[mh * 4 + fm][nh * 2 + fn], 0, 0, 0);
      __builtin_amdgcn_s_setprio(0);
    }
    bar();  // all waves done reading buf[cur]
    if (kt + 2 < 16) {
      STAGE(kt + 2, cur);                               // into freed buffer
      asm volatile("s_waitcnt vmcnt(8)" ::: "memory");  // tile kt+1 arrived; kt+2 in flight
    } else if (kt + 1 < 16) {
      asm volatile("s_waitcnt vmcnt(0)" ::: "memory");  // epilogue drain
    }
    bar();
  }

  const int erow = (lane >> 4) * 4, ecol = lane & 15;
  if constexpr (KINDS == 4) {
    const int dd = t & 63;
    const int gd = bn * 64 + dd;
    const float br = bih[gd] + bhh[gd];
    const float bz = bih[512 + gd] + bhh[512 + gd];
    const float bi = bih[1024 + gd];
    const float bh = bhh[1024 + gd];
    const int rowbase = (t >> 6) * 16;
#pragma unroll
    for (int W2 = 0; W2 < 2; ++W2) {  // 128-row chunks through LDS [128][256 f32]
      if (wm == W2) {
#pragma unroll
        for (int fm = 0; fm < 8; ++fm)
#pragma unroll
          for (int fn = 0; fn < 4; ++fn)
#pragma unroll
            for (int j = 0; j < 4; ++j) {
              const int row = fm * 16 + erow + j;
              const int c4 = (wn * 64 + fn * 16 + ecol) * 4;
              *(float*)(smem + row * 1024 + (c4 ^ ((row & 7) << 4))) = acc[fm][fn][j];
            }
      }
      asm volatile("s_waitcnt lgkmcnt(0)" ::: "memory");
      bar();
#pragma unroll
      for (int j = 0; j < 16; ++j) {
        const int row = rowbase + j;
        const int x = (row & 7) << 4;
        const float a0 = *(const float*)(smem + row * 1024 + (((dd) * 4) ^ x));
        const float a1 = *(const float*)(smem + row * 1024 + (((64 + dd) * 4) ^ x));
        const float a2 = *(const float*)(smem + row * 1024 + (((128 + dd) * 4) ^ x));
        const float a3 = *(const float*)(smem + row * 1024 + (((192 + dd) * 4) ^ x));
        const float rv = sigmf(a0 + br);
        const float zv = sigmf(a1 + bz);
        const float nv = tanhf_(a2 + bi + rv * (a3 + bh));
        const size_t off = (size_t)(bm * 256 + W2 * 128 + row) * 512 + gd;
        const float hv = (1.0f - zv) * nv + zv * bf2f(hold[off]);
        outB[off] = f2bf(hv);
      }
      bar();
    }
  } else {
#pragma unroll
    for (int fm = 0; fm < 8; ++fm)
#pragma unroll
      for (int fn = 0; fn < 4; ++fn) {
        const int col = bn * 256 + wn * 64 + fn * 16 + ecol;
#pragma unroll
        for (int j = 0; j < 4; ++j) {
          const size_t off = (size_t)(bm * 256 + wm * 128 + fm * 16 + erow + j) * 512 + col;
          const float v = acc[fm][fn][j];
          outB[off] = f2bf(v);
          if (writeF) outF[off] = v;
        }
      }
  }
}

extern "C" void kernel_launch(void* const* d_in, const int* in_sizes, int n_in,
                              void* d_out, int out_size, void* d_ws, size_t ws_size,
                              hipStream_t stream) {
  const float* x   = (const float*)d_in[0];
  const float* wih = (const float*)d_in[1];
  const float* whh = (const float*)d_in[2];
  const float* bih = (const float*)d_in[3];
  const float* bhh = (const float*)d_in[4];
  const float* w1  = (const float*)d_in[5];
  const float* w2  = (const float*)d_in[6];

  char* ws = (char*)d_ws;
  const size_t bd2 = (size_t)BD * 2;
  unsigned short* xall  = (unsigned short*)ws;                    // 8 x 32 MB
  unsigned short* hb[2] = {(unsigned short*)(ws + 8 * bd2),
                           (unsigned short*)(ws + 9 * bd2)};      // 32 MB each
  unsigned short* Wg = (unsigned short*)(ws + 10 * bd2);          // 4 MB
  unsigned short* Wm = Wg + 2048 * 1024;                          // 1 MB

  hipMemsetAsync(hb[0], 0, bd2, stream);  // h0 = 0
  cvt_bf16_all<<<65536, 256, 0, stream>>>(x, xall);
  prep_w<<<10240, 256, 0, stream>>>(wih, whh, w1, w2, Wg, Wm);

  int hp = 0;
  for (int i = 0; i < 8; ++i) {
    const unsigned short* xi = xall + (size_t)i * BD;
    gemm8<4, 8><<<1024, 512, 0, stream>>>(xi, hb[hp], Wg, bih, bhh, hb[hp],
                                          hb[hp ^ 1], nullptr, 0);
    hp ^= 1;
    if (i & 1) {
      const unsigned short* xprev = xall + (size_t)(i - 1) * BD;
      gemm8<1, 2><<<256, 512, 0, stream>>>(hb[hp], xprev, Wm, nullptr, nullptr, nullptr,
                                           hb[hp ^ 1], (float*)d_out, (i == 7) ? 1 : 0);
      hp ^= 1;
    }
  }
}

// Round 3
// 1274.669 us; speedup vs baseline: 1.4149x; 1.4149x over previous
//
#include <hip/hip_runtime.h>

// RSNEncoder R3: unpadded gates GEMM (256x64x[3 gates]) + true per-phase
// counted-vmcnt schedule (m201 discipline): each phase = {ds_read frags,
// stage-issue, counted vmcnt (BEFORE barrier -> cross-wave arrival), barrier,
// lgkmcnt(0), setprio+16 MFMA, barrier}. LDS XOR-swizzled (T2), XCD swizzle (T1).

#define BDIM 32768
#define DDIM 512
#define BD (BDIM * DDIM)

typedef short bf16x8 __attribute__((ext_vector_type(8)));
typedef float f32x4 __attribute__((ext_vector_type(4)));
typedef unsigned short u16x8 __attribute__((ext_vector_type(8)));

#define AS1 __attribute__((address_space(1)))
#define AS3 __attribute__((address_space(3)))

__device__ __forceinline__ unsigned short f2bf(float f) {
  union { float f; unsigned u; } v; v.f = f;
  return (unsigned short)((v.u + 0x7fffu + ((v.u >> 16) & 1u)) >> 16);  // RNE
}
__device__ __forceinline__ float bf2f(unsigned short b) {
  union { unsigned u; float f; } v; v.u = (unsigned)b << 16; return v.f;
}
__device__ __forceinline__ float sigmf(float x) { return 1.0f / (1.0f + __expf(-x)); }
__device__ __forceinline__ float tanhf_(float x) { return 1.0f - 2.0f / (__expf(2.0f * x) + 1.0f); }
__device__ __forceinline__ void bar() { asm volatile("s_barrier" ::: "memory"); }
#define LGKM0 asm volatile("s_waitcnt lgkmcnt(0)" ::: "memory")
#define VMCNT(n) asm volatile("s_waitcnt vmcnt(" #n ")" ::: "memory")

// ---- fp32 -> bf16, grid-stride ----
__global__ void cvt_bf16_all(const float* __restrict__ in, unsigned short* __restrict__ out) {
  const size_t stride = (size_t)gridDim.x * 256;
  for (size_t i = (size_t)blockIdx.x * 256 + threadIdx.x; i < (size_t)BD; i += stride) {
    const size_t o = i * 8;
    const float4 a = *(const float4*)(in + o);
    const float4 b = *(const float4*)(in + o + 4);
    u16x8 v;
    v[0] = f2bf(a.x); v[1] = f2bf(a.y); v[2] = f2bf(a.z); v[3] = f2bf(a.w);
    v[4] = f2bf(b.x); v[5] = f2bf(b.y); v[6] = f2bf(b.z); v[7] = f2bf(b.w);
    *(u16x8*)(out + o) = v;
  }
}

// ---- weight prep: Wg[1536][1024] = [Wih | Whh] (rows r,z,n); Wm[512][1024] = [w1 | w2] ----
__global__ void prep_w(const float* __restrict__ wih, const float* __restrict__ whh,
                       const float* __restrict__ w1, const float* __restrict__ w2,
                       unsigned short* __restrict__ Wg, unsigned short* __restrict__ Wm) {
  int i = blockIdx.x * 256 + threadIdx.x;
  if (i < 1536 * 1024) {
    const int j = i >> 10, k = i & 1023;
    Wg[i] = f2bf((k < 512) ? wih[j * 512 + k] : whh[j * 512 + (k - 512)]);
  } else {
    i -= 1536 * 1024;
    const int j = i >> 10, k = i & 1023;
    Wm[i] = f2bf((k < 512) ? w1[j * 512 + k] : w2[j * 512 + (k - 512)]);
  }
}

template <int SET>
__device__ __forceinline__ void mfma16(f32x4 (&acc)[4][4][2], const bf16x8 (&av)[4][2],
                                       const bf16x8 (&bv)[2][2]) {
  __builtin_amdgcn_s_setprio(1);
#pragma unroll
  for (int fm = 0; fm < 4; ++fm)
#pragma unroll
    for (int fn = 0; fn < 2; ++fn)
#pragma unroll
      for (int ks = 0; ks < 2; ++ks)
        acc[SET][fm][fn] = __builtin_amdgcn_mfma_f32_16x16x32_bf16(
            av[fm][ks], bv[fn][ks], acc[SET][fm][fn], 0, 0, 0);
  __builtin_amdgcn_s_setprio(0);
}

// ================= gates kernel: h_new = GRU(x, h) =================
// Block: 256 rows x 64 d-cols. LDS/buf: A[256][128B] + 3x B[64][128B] = 56 KB, x2.
// K-tile = 64 (16 tiles; kt<8 from X, kt>=8 from H). 3 phases/tile (r,z,n).
__global__ __launch_bounds__(512, 2) void gru_gates(
    const unsigned short* __restrict__ X, const unsigned short* __restrict__ H,
    const unsigned short* __restrict__ Wg, const float* __restrict__ bih,
    const float* __restrict__ bhh, unsigned short* __restrict__ outB) {
  __shared__ char smem[114688];
  const int t = threadIdx.x;
  const int lane = t & 63, wid = t >> 6;
  const int wm = wid >> 1, wn = wid & 1;     // wave tile 64 rows x 32 cols
  const int xcd = blockIdx.x & 7, ixc = blockIdx.x >> 3;
  const int bm = xcd * 16 + (ixc >> 3);      // 128 row-blocks
  const int bn = ixc & 7;                    // 8 d-blocks

  f32x4 acc[4][4][2];
  const f32x4 z4 = {0.f, 0.f, 0.f, 0.f};
#pragma unroll
  for (int s = 0; s < 4; ++s)
#pragma unroll
    for (int a = 0; a < 4; ++a)
#pragma unroll
      for (int b = 0; b < 2; ++b) acc[s][a][b] = z4;

  // staging source offsets (pre-swizzled col slot; rule #21)
  const int trow = t >> 3;
  const int tswz = ((t & 7) * 16) ^ ((trow & 7) << 4);
  int asrc[4], bsrc[3];
#pragma unroll
  for (int i = 0; i < 4; ++i) asrc[i] = (bm * 256 + i * 64 + trow) * 1024 + tswz;
#pragma unroll
  for (int g = 0; g < 3; ++g) bsrc[g] = (g * 512 + bn * 64 + trow) * 2048 + tswz;

  const char* Xc = (const char*)X;
  const char* Hc = (const char*)H;
  const char* Wc = (const char*)Wg;

  auto issA = [&](int kt, int i) {
    const char* base = ((kt < 8) ? Xc : Hc) + (kt & 7) * 128 + asrc[i];
    char* dst = smem + (kt & 1) * 57344 + i * 8192 + t * 16;
    __builtin_amdgcn_global_load_lds((const AS1 void*)base, (AS3 void*)dst, 16, 0, 0);
  };
  auto issB = [&](int kt, int g) {
    const char* base = Wc + kt * 128 + bsrc[g];
    char* dst = smem + (kt & 1) * 57344 + 32768 + g * 8192 + t * 16;
    __builtin_amdgcn_global_load_lds((const AS1 void*)base, (AS3 void*)dst, 16, 0, 0);
  };

  bf16x8 av[4][2], bv[2][2];
  auto readA = [&](const char* pa) {
#pragma unroll
    for (int fm = 0; fm < 4; ++fm)
#pragma unroll
      for (int ks = 0; ks < 2; ++ks) {
        const int r = wm * 64 + fm * 16 + (lane & 15);
        const int c = ks * 64 + (lane >> 4) * 16;
        av[fm][ks] = *(const bf16x8*)(pa + r * 128 + (c ^ ((r & 7) << 4)));
      }
  };
  auto readB = [&](const char* pb, int g) {
#pragma unroll
    for (int fn = 0; fn < 2; ++fn)
#pragma unroll
      for (int ks = 0; ks < 2; ++ks) {
        const int r = wn * 32 + fn * 16 + (lane & 15);
        const int c = ks * 64 + (lane >> 4) * 16;
        bv[fn][ks] = *(const bf16x8*)(pb + g * 8192 + r * 128 + (c ^ ((r & 7) << 4)));
      }
  };

  // prologue: tile 0, issue order A0..3,B0,B1,B2 (= steady-state order)
  issA(0, 0); issA(0, 1); issA(0, 2); issA(0, 3);
  issB(0, 0); issB(0, 1); issB(0, 2);
  VMCNT(2);  // A0..3,B0 arrived (p0's needs); publish via barrier
  bar();

#pragma unroll
  for (int half = 0; half < 2; ++half) {
    for (int k8 = 0; k8 < 8; ++k8) {
      const int kt = half * 8 + k8;
      const bool last = (half == 1) && (k8 == 7);
      const char* pa = smem + (kt & 1) * 57344;
      const char* pb = pa + 32768;
      // ---- phase 0: gate r ----
      readA(pa);
      readB(pb, 0);
      if (!last) {
        issA(kt + 1, 0); issA(kt + 1, 1); issA(kt + 1, 2);
        VMCNT(4);  // kt's B1 arrived (allow: kt B2 + 3 new)
      } else {
        VMCNT(1);
      }
      bar(); LGKM0;
      mfma16<0>(acc, av, bv);
      bar();
      // ---- phase 1: gate z ----
      readB(pb, 1);
      if (!last) {
        issA(kt + 1, 3); issB(kt + 1, 0);
        VMCNT(5);  // kt's B2 arrived (allow: 5 new)
      } else {
        VMCNT(0);
      }
      bar(); LGKM0;
      mfma16<1>(acc, av, bv);
      bar();
      // ---- phase 2: gate n ----
      readB(pb, 2);
      if (!last) {
        issB(kt + 1, 1); issB(kt + 1, 2);
        VMCNT(2);  // kt+1's A0..3,B0 arrived (allow: kt+1 B1,B2)
      }
      bar(); LGKM0;
      if (half == 0) mfma16<2>(acc, av, bv);  // i_n (K<512)
      else           mfma16<3>(acc, av, bv);  // h_n (K>=512)
      bar();
    }
  }

  // ---- epilogue: gate math, direct (all 4 pieces local) ----
  const int erow = (lane >> 4) * 4, ecol = lane & 15;
#pragma unroll
  for (int fn = 0; fn < 2; ++fn) {
    const int d = bn * 64 + wn * 32 + fn * 16 + ecol;
    const float br = bih[d] + bhh[d];
    const float bz = bih[512 + d] + bhh[512 + d];
    const float bi = bih[1024 + d];
    const float bh = bhh[1024 + d];
#pragma unroll
    for (int fm = 0; fm < 4; ++fm)
#pragma unroll
      for (int j = 0; j < 4; ++j) {
        const int row = bm * 256 + wm * 64 + fm * 16 + erow + j;
        const size_t off = (size_t)row * 512 + d;
        const float rv = sigmf(acc[0][fm][fn][j] + br);
        const float zv = sigmf(acc[1][fm][fn][j] + bz);
        const float nv = tanhf_(acc[2][fm][fn][j] + bi + rv * (acc[3][fm][fn][j] + bh));
        outB[off] = f2bf((1.0f - zv) * nv + zv * bf2f(H[off]));
      }
  }
}

// ================= mixed kernel: out = A @ [w1|w2]^T =================
// 256x256 tile, quadrant phases with half-tile mapping: phase (mh,nh) needs
// only A-half mh / B-half nh. Issue order per tile: Ah0,Bh0,Bh1,Ah1.
template <int MH, int NH>
__device__ __forceinline__ void mfmaQ(f32x4 (&acc)[8][4], const bf16x8 (&af)[4][2],
                                      const bf16x8 (&bv)[2][2]) {
  __builtin_amdgcn_s_setprio(1);
#pragma unroll
  for (int fm = 0; fm < 4; ++fm)
#pragma unroll
    for (int fn = 0; fn < 2; ++fn)
#pragma unroll
      for (int ks = 0; ks < 2; ++ks)
        acc[MH * 4 + fm][NH * 2 + fn] = __builtin_amdgcn_mfma_f32_16x16x32_bf16(
            af[fm][ks], bv[fn][ks], acc[MH * 4 + fm][NH * 2 + fn], 0, 0, 0);
  __builtin_amdgcn_s_setprio(0);
}

template <int WF>
__global__ __launch_bounds__(512, 2) void mixed_gemm(
    const unsigned short* __restrict__ Ka, const unsigned short* __restrict__ Kb,
    const unsigned short* __restrict__ Wm,
    unsigned short* __restrict__ outB, float* __restrict__ outF) {
  __shared__ char smem[131072];
  const int t = threadIdx.x;
  const int lane = t & 63, wid = t >> 6;
  const int wm = wid >> 2, wn = wid & 3;  // with halves: wave = 128 rows x 64 cols
  const int xcd = blockIdx.x & 7, ixc = blockIdx.x >> 3;
  const int bm = xcd * 16 + (ixc >> 1);
  const int bn = ixc & 1;

  f32x4 acc[8][4];
  const f32x4 z4 = {0.f, 0.f, 0.f, 0.f};
#pragma unroll
  for (int a = 0; a < 8; ++a)
#pragma unroll
    for (int b = 0; b < 4; ++b) acc[a][b] = z4;

  const int trow = t >> 3;
  const int tswz = ((t & 7) * 16) ^ ((trow & 7) << 4);
  int asrc[4], bsrc[4];
#pragma unroll
  for (int i = 0; i < 4; ++i) {
    asrc[i] = (bm * 256 + i * 64 + trow) * 1024 + tswz;
    bsrc[i] = (bn * 256 + i * 64 + trow) * 2048 + tswz;
  }
  const char* Kac = (const char*)Ka;
  const char* Kbc = (const char*)Kb;
  const char* Wc = (const char*)Wm;

  auto issA = [&](int kt, int i) {
    const char* base = ((kt < 8) ? Kac : Kbc) + (kt & 7) * 128 + asrc[i];
    char* dst = smem + (kt & 1) * 65536 + i * 8192 + t * 16;
    __builtin_amdgcn_global_load_lds((const AS1 void*)base, (AS3 void*)dst, 16, 0, 0);
  };
  auto issB = [&](int kt, int i) {
    const char* base = Wc + kt * 128 + bsrc[i];
    char* dst = smem + (kt & 1) * 65536 + 32768 + i * 8192 + t * 16;
    __builtin_amdgcn_global_load_lds((const AS1 void*)base, (AS3 void*)dst, 16, 0, 0);
  };

  bf16x8 af[4][2], bf0[2][2], bf1[2][2];
  auto readAm = [&](const char* pa, int mh) {
#pragma unroll
    for (int fm = 0; fm < 4; ++fm)
#pragma unroll
      for (int ks = 0; ks < 2; ++ks) {
        const int r = mh * 128 + wm * 64 + fm * 16 + (lane & 15);
        const int c = ks * 64 + (lane >> 4) * 16;
        af[fm][ks] = *(const bf16x8*)(pa + r * 128 + (c ^ ((r & 7) << 4)));
      }
  };
  auto readBm = [&](const char* pb, int nh, bf16x8 (&bv)[2][2]) {
#pragma unroll
    for (int fn = 0; fn < 2; ++fn)
#pragma unroll
      for (int ks = 0; ks < 2; ++ks) {
        const int r = nh * 128 + wn * 32 + fn * 16 + (lane & 15);
        const int c = ks * 64 + (lane >> 4) * 16;
        bv[fn][ks] = *(const bf16x8*)(pb + r * 128 + (c ^ ((r & 7) << 4)));
      }
  };

  // prologue, issue order Ah0(A0,A1), Bh0(B0,B1), Bh1(B2,B3), Ah1(A2,A3)
  issA(0, 0); issA(0, 1); issB(0, 0); issB(0, 1);
  issB(0, 2); issB(0, 3); issA(0, 2); issA(0, 3);
  VMCNT(4);  // Ah0+Bh0 arrived
  bar();

  for (int kt = 0; kt < 16; ++kt) {
    const bool last = (kt == 15);
    const char* pa = smem + (kt & 1) * 65536;
    const char* pb = pa + 32768;
    // p0: (mh0, nh0)
    readAm(pa, 0);
    readBm(pb, 0, bf0);
    if (!last) { issA(kt + 1, 0); issA(kt + 1, 1); VMCNT(4); }  // kt's Bh1 arrived
    else       { VMCNT(2); }
    bar(); LGKM0;
    mfmaQ<0, 0>(acc, af, bf0);
    bar();
    // p1: (mh0, nh1)
    readBm(pb, 1, bf1);
    if (!last) { issB(kt + 1, 0); issB(kt + 1, 1); VMCNT(4); }  // kt's Ah1 arrived
    else       { VMCNT(0); }
    bar(); LGKM0;
    mfmaQ<0, 1>(acc, af, bf1);
    bar();
    // p2: (mh1, nh0)
    readAm(pa, 1);
    if (!last) { issB(kt + 1, 2); issB(kt + 1, 3); }
    bar(); LGKM0;
    mfmaQ<1, 0>(acc, af, bf0);
    bar();
    // p3: (mh1, nh1) — no ds_reads (register reuse)
    if (!last) { issA(kt + 1, 2); issA(kt + 1, 3); VMCNT(4); }  // kt+1's Ah0+Bh0 arrived
    bar();
    mfmaQ<1, 1>(acc, af, bf1);
    bar();
  }

  const int erow = (lane >> 4) * 4, ecol = lane & 15;
#pragma unroll
  for (int mh = 0; mh < 2; ++mh)
#pragma unroll
    for (int fm = 0; fm < 4; ++fm)
#pragma unroll
      for (int nh = 0; nh < 2; ++nh)
#pragma unroll
        for (int fn = 0; fn < 2; ++fn) {
          const int col = bn * 256 + nh * 128 + wn * 32 + fn * 16 + ecol;
#pragma unroll
          for (int j = 0; j < 4; ++j) {
            const int row = bm * 256 + mh * 128 + wm * 64 + fm * 16 + erow + j;
            const size_t off = (size_t)row * 512 + col;
            const float v = acc[mh * 4 + fm][nh * 2 + fn][j];
            if constexpr (WF) outF[off] = v;
            else              outB[off] = f2bf(v);
          }
        }
}

extern "C" void kernel_launch(void* const* d_in, const int* in_sizes, int n_in,
                              void* d_out, int out_size, void* d_ws, size_t ws_size,
                              hipStream_t stream) {
  const float* x   = (const float*)d_in[0];
  const float* wih = (const float*)d_in[1];
  const float* whh = (const float*)d_in[2];
  const float* bih = (const float*)d_in[3];
  const float* bhh = (const float*)d_in[4];
  const float* w1  = (const float*)d_in[5];
  const float* w2  = (const float*)d_in[6];

  char* ws = (char*)d_ws;
  const size_t bd2 = (size_t)BD * 2;
  unsigned short* xall  = (unsigned short*)ws;                  // 8 x 32 MB
  unsigned short* hb[2] = {(unsigned short*)(ws + 8 * bd2),
                           (unsigned short*)(ws + 9 * bd2)};    // 32 MB each
  unsigned short* Wg = (unsigned short*)(ws + 10 * bd2);        // 3 MB
  unsigned short* Wm = Wg + 1536 * 1024;                        // 1 MB

  hipMemsetAsync(hb[0], 0, bd2, stream);  // h0 = 0
  cvt_bf16_all<<<2048, 256, 0, stream>>>(x, xall);
  prep_w<<<8192, 256, 0, stream>>>(wih, whh, w1, w2, Wg, Wm);

  int hp = 0;
  for (int i = 0; i < 8; ++i) {
    const unsigned short* xi = xall + (size_t)i * BD;
    gru_gates<<<1024, 512, 0, stream>>>(xi, hb[hp], Wg, bih, bhh, hb[hp ^ 1]);
    hp ^= 1;
    if (i & 1) {
      const unsigned short* xprev = xall + (size_t)(i - 1) * BD;
      if (i == 7)
        mixed_gemm<1><<<256, 512, 0, stream>>>(hb[hp], xprev, Wm, nullptr, (float*)d_out);
      else
        mixed_gemm<0><<<256, 512, 0, stream>>>(hb[hp], xprev, Wm, hb[hp ^ 1], nullptr);
      if (i != 7) hp ^= 1;
    }
  }
}